// Round 3
// baseline (762.529 us; speedup 1.0000x reference)
//
#include <hip/hip_runtime.h>

#define HWn 3136
#define W56 56
#define Bn  16
#define CIN0 512

typedef unsigned short ushortT;
typedef __attribute__((ext_vector_type(8))) short bf16x8;
typedef __attribute__((ext_vector_type(4))) float f32x4;

__device__ inline ushortT bf_hi(float v) {
    unsigned u = __float_as_uint(v);
    unsigned r = u + 0x7FFFu + ((u >> 16) & 1u);
    return (ushortT)(r >> 16);
}
__device__ inline float bf_f(ushortT h) { return __uint_as_float(((unsigned)h) << 16); }

// ---------------- zero small f32 buffer ----------------
__global__ void zero_kernel(float* __restrict__ p, int n)
{
    int i = blockIdx.x * 256 + threadIdx.x;
    if (i < n) p[i] = 0.f;
}

// ---------------- fused: spatial-mask logit partials + pooled mean of x ----------------
// grid (25 p-tiles, 8 c-tiles, B); block 256. Reads x once.
__global__ __launch_bounds__(256) void mask_pool_kernel(
    const float* __restrict__ x, const float* __restrict__ smw,
    float* __restrict__ slog_part, float* __restrict__ pooled)
{
    __shared__ float s_t[64][129];
    __shared__ float s_w[64];
    __shared__ float s_slog[128];
    __shared__ float s_pool[4][64];
    const int b = blockIdx.z, ct = blockIdx.y, pt = blockIdx.x;
    const int c0 = ct * 64, p0 = pt * 128;
    const int t = threadIdx.x;
    if (t < 64) s_w[t] = smw[c0 + t];
    __syncthreads();
    const int pi = t & 127, par = t >> 7;
    const int p = p0 + pi;
    const bool pv = (p < HWn);
    const float* xb = x + ((size_t)b * 512 + c0) * HWn;
    float sacc = 0.f;
#pragma unroll 4
    for (int rep = 0; rep < 32; ++rep) {
        int ci = rep * 2 + par;
        float v = pv ? xb[(size_t)ci * HWn + p] : 0.f;
        s_t[ci][pi] = v;
        sacc = fmaf(v, s_w[ci], sacc);
    }
    if (par == 0) s_slog[pi] = sacc;
    __syncthreads();
    if (par == 1) s_slog[pi] += sacc;
    __syncthreads();
    if (t < 128 && p0 + t < HWn)
        slog_part[((size_t)b * 8 + ct) * HWn + p0 + t] = s_slog[t];
    // pooled: sum over p per channel
    const int c = t & 63, pg = t >> 6;       // 4 p-groups of 32
    float a = 0.f;
#pragma unroll 8
    for (int it = 0; it < 32; ++it) a += s_t[c][pg * 32 + it];
    s_pool[pg], __syncthreads();             // (sequence point only)
    s_pool[pg][c] = a;
    __syncthreads();
    if (t < 64) {
        float s = s_pool[0][t] + s_pool[1][t] + s_pool[2][t] + s_pool[3][t];
        atomicAdd(&pooled[b * 512 + c0 + t], s * (1.f / 3136.f));
    }
}

// ---------------- threshold: smask from deterministic partial sums ----------------
__global__ void thresh_kernel(const float* __restrict__ slog_part,
                              const float* __restrict__ smb, float* __restrict__ smask)
{
    int e = blockIdx.x * 256 + threadIdx.x;
    if (e >= Bn * HWn) return;
    int b = e / HWn, p = e % HWn;
    float s = smb[0];
#pragma unroll
    for (int i = 0; i < 8; ++i) s += slog_part[((size_t)b * 8 + i) * HWn + p];
    smask[e] = (s > 0.f) ? 1.f : 0.f;
}

// ---------------- 3x3 max dilation ----------------
__global__ __launch_bounds__(256) void dilate_kernel(const float* __restrict__ sm, float* __restrict__ sd)
{
    int b = blockIdx.x;
    int p = blockIdx.y * 256 + threadIdx.x;
    if (p >= HWn) return;
    int py = p / W56, px = p % W56;
    float m = 0.f;
    for (int dy = -1; dy <= 1; ++dy) {
        int sy = py + dy; if (sy < 0 || sy >= W56) continue;
        for (int dx = -1; dx <= 1; ++dx) {
            int sx = px + dx; if (sx < 0 || sx >= W56) continue;
            m = fmaxf(m, sm[b * HWn + sy * W56 + sx]);
        }
    }
    sd[b * HWn + p] = m;
}

// ---------------- pooled mean over P of transposed split-bf16 [B][P][128] ----------------
__global__ __launch_bounds__(256) void pool_meanT_kernel(const ushortT* __restrict__ hi,
        const ushortT* __restrict__ lo, float* __restrict__ pooled)
{
    int b = blockIdx.x, slice = blockIdx.y;
    int t = threadIdx.x;
    int c4 = (t & 31) * 4, rg = t >> 5;
    float a0 = 0.f, a1 = 0.f, a2 = 0.f, a3 = 0.f;
    for (int it = 0; it < 49; ++it) {
        int p = slice * 392 + rg + it * 8;
        size_t base = ((size_t)b * HWn + p) * 128 + c4;
        ushort4 h4 = *(const ushort4*)&hi[base];
        ushort4 l4 = *(const ushort4*)&lo[base];
        a0 += bf_f(h4.x) + bf_f(l4.x);
        a1 += bf_f(h4.y) + bf_f(l4.y);
        a2 += bf_f(h4.z) + bf_f(l4.z);
        a3 += bf_f(h4.w) + bf_f(l4.w);
    }
    __shared__ float red[8][128];
    red[rg][c4] = a0; red[rg][c4 + 1] = a1; red[rg][c4 + 2] = a2; red[rg][c4 + 3] = a3;
    __syncthreads();
    if (t < 128) {
        float s = 0.f;
#pragma unroll
        for (int g = 0; g < 8; ++g) s += red[g][t];
        atomicAdd(&pooled[b * 128 + t], s * (1.f / 3136.f));
    }
}

// ---------------- channel mask ----------------
__global__ void chan_mask_kernel(const float* __restrict__ pooled, const float* __restrict__ Wm,
                                 const float* __restrict__ bias, float* __restrict__ mask,
                                 int Cin, int Cout)
{
    int b = blockIdx.x, o = threadIdx.x;
    if (o >= Cout) return;
    const float* pr = pooled + (size_t)b * Cin;
    const float* wr = Wm + (size_t)o * Cin;
    float s = bias[o];
    for (int c = 0; c < Cin; ++c) s = fmaf(pr[c], wr[c], s);
    mask[b * Cout + o] = (s > 0.f) ? 1.f : 0.f;
}

// ---------------- weight split kernels ----------------
__global__ void split_w_kernel(const float* __restrict__ w, ushortT* __restrict__ hi,
                               ushortT* __restrict__ lo, int n)
{
    int i = blockIdx.x * 256 + threadIdx.x;
    if (i >= n) return;
    float v = w[i];
    ushortT h = bf_hi(v);
    hi[i] = h;
    lo[i] = bf_hi(v - bf_f(h));
}

__global__ void split_w2_kernel(const float* __restrict__ w2, ushortT* __restrict__ hi,
                                ushortT* __restrict__ lo)
{
    int e = blockIdx.x * 256 + threadIdx.x;   // [tap][o][c]
    if (e >= 9 * 128 * 128) return;
    int c = e & 127, o = (e >> 7) & 127, tap = e >> 14;
    float v = w2[((size_t)o * 128 + c) * 9 + tap];
    ushortT h = bf_hi(v);
    hi[e] = h;
    lo[e] = bf_hi(v - bf_f(h));
}

// ---------------- MFMA split-bf16 conv ----------------
// Block: 64 O x 128 P, K-step 32, 2 waves of 64x64 (4x4 frags of 16x16x32).
template<int KC, int TAPS, bool RELU, bool IN_F32, bool OUT_F32>
__global__ __launch_bounds__(128) void mfma_conv_kernel(
    const float* __restrict__ in_f32,
    const ushortT* __restrict__ in_hi, const ushortT* __restrict__ in_lo,
    const ushortT* __restrict__ wh, const ushortT* __restrict__ wl,
    const float* __restrict__ bias, const float* __restrict__ cmask,
    const float* __restrict__ pmask,
    float* __restrict__ out_f32, ushortT* __restrict__ out_hi, ushortT* __restrict__ out_lo,
    int Cout)
{
    __shared__ __align__(16) ushortT As_hi[64 * 40], As_lo[64 * 40];
    __shared__ __align__(16) ushortT Bs_hi[128 * 40], Bs_lo[128 * 40];
    __shared__ float s_bias[64], s_cm[64];

    const int b  = blockIdx.z;
    const int o0 = blockIdx.y * 64;
    const int p0 = blockIdx.x * 128;
    const int tid = threadIdx.x;
    const int lane = tid & 63;
    const int g  = lane >> 4;
    const int lc = lane & 15;
    const int wn = tid >> 6;           // 0..1, owns p-half

    if (tid < 64) {
        s_bias[tid] = bias[o0 + tid];
        s_cm[tid]   = cmask[b * Cout + o0 + tid];
    }

    int aoff[4], boff[4];
#pragma unroll
    for (int m = 0; m < 4; ++m) aoff[m] = (m * 16 + lc) * 40 + g * 8;
#pragma unroll
    for (int n = 0; n < 4; ++n) boff[n] = (wn * 64 + n * 16 + lc) * 40 + g * 8;

    f32x4 acc[4][4];
#pragma unroll
    for (int m = 0; m < 4; ++m)
#pragma unroll
        for (int n = 0; n < 4; ++n) acc[m][n] = (f32x4){0.f, 0.f, 0.f, 0.f};

    for (int tap = 0; tap < TAPS; ++tap) {
        const int dy = (TAPS == 9) ? (tap / 3 - 1) : 0;
        const int dx = (TAPS == 9) ? (tap % 3 - 1) : 0;
        for (int kc = 0; kc < KC; kc += 32) {
            __syncthreads();
            // ---- stage A (weights): 64 rows x 32 k ----
#pragma unroll
            for (int i = 0; i < 2; ++i) {
                int u = tid + i * 128;
                int row = u >> 2, ch = u & 3;
                size_t srow = (TAPS == 9) ? (((size_t)tap * 128 + o0 + row) * 128 + kc)
                                          : ((size_t)(o0 + row) * KC + kc);
                *(uint4*)&As_hi[row * 40 + ch * 8] = *(const uint4*)(wh + srow + ch * 8);
                *(uint4*)&As_lo[row * 40 + ch * 8] = *(const uint4*)(wl + srow + ch * 8);
            }
            // ---- stage B (activations): 128 rows x 32 k ----
            if (IN_F32) {
                // lane owns pixel p=tid; packed-uint b32 writes, conflict-free
                const float* inB = in_f32 + (size_t)b * KC * HWn;
                const int p = tid;
                const int gp = p0 + p;
                const bool pv = (gp < HWn);
                uint* bh32 = (uint*)Bs_hi;
                uint* bl32 = (uint*)Bs_lo;
#pragma unroll
                for (int j = 0; j < 16; ++j) {
                    float v0 = pv ? inB[(size_t)(kc + 2 * j) * HWn + gp] : 0.f;
                    float v1 = pv ? inB[(size_t)(kc + 2 * j + 1) * HWn + gp] : 0.f;
                    ushortT h0 = bf_hi(v0), h1 = bf_hi(v1);
                    ushortT l0 = bf_hi(v0 - bf_f(h0)), l1 = bf_hi(v1 - bf_f(h1));
                    bh32[p * 20 + j] = (uint)h0 | ((uint)h1 << 16);
                    bl32[p * 20 + j] = (uint)l0 | ((uint)l1 << 16);
                }
            } else {
#pragma unroll
                for (int i = 0; i < 4; ++i) {
                    int u = tid + i * 128;
                    int row = u >> 2, ch = u & 3;
                    int pg = p0 + row;
                    int q = pg;
                    bool valid;
                    if (TAPS == 9) {
                        int py = pg / 56, px = pg % 56;
                        int sy = py + dy, sx = px + dx;
                        valid = (pg < HWn) && (sy >= 0) && (sy < 56) && (sx >= 0) && (sx < 56);
                        q = sy * 56 + sx;
                    } else {
                        valid = (pg < HWn);
                    }
                    uint4 vh = make_uint4(0u, 0u, 0u, 0u), vl = vh;
                    if (valid) {
                        size_t sb = ((size_t)b * HWn + q) * KC + kc + ch * 8;
                        vh = *(const uint4*)(in_hi + sb);
                        vl = *(const uint4*)(in_lo + sb);
                    }
                    *(uint4*)&Bs_hi[row * 40 + ch * 8] = vh;
                    *(uint4*)&Bs_lo[row * 40 + ch * 8] = vl;
                }
            }
            __syncthreads();
            // ---- compute: 16 frags x 3 MFMA ----
            bf16x8 a_h[4], a_l[4];
#pragma unroll
            for (int m = 0; m < 4; ++m) {
                a_h[m] = *(const bf16x8*)&As_hi[aoff[m]];
                a_l[m] = *(const bf16x8*)&As_lo[aoff[m]];
            }
#pragma unroll
            for (int n = 0; n < 4; ++n) {
                bf16x8 b_h = *(const bf16x8*)&Bs_hi[boff[n]];
                bf16x8 b_l = *(const bf16x8*)&Bs_lo[boff[n]];
#pragma unroll
                for (int m = 0; m < 4; ++m) {
                    acc[m][n] = __builtin_amdgcn_mfma_f32_16x16x32_bf16(a_h[m], b_h, acc[m][n], 0, 0, 0);
                    acc[m][n] = __builtin_amdgcn_mfma_f32_16x16x32_bf16(a_h[m], b_l, acc[m][n], 0, 0, 0);
                    acc[m][n] = __builtin_amdgcn_mfma_f32_16x16x32_bf16(a_l[m], b_h, acc[m][n], 0, 0, 0);
                }
            }
        }
    }

    // ---- epilogue ----
#pragma unroll
    for (int m = 0; m < 4; ++m) {
        int ob = m * 16 + g * 4;
        f32x4 b4 = *(const f32x4*)&s_bias[ob];
        f32x4 c4 = *(const f32x4*)&s_cm[ob];
#pragma unroll
        for (int n = 0; n < 4; ++n) {
            int p = p0 + wn * 64 + n * 16 + lc;
            if (p >= HWn) continue;
            float pm = pmask[b * HWn + p];
            float v[4];
#pragma unroll
            for (int r = 0; r < 4; ++r) {
                float t = acc[m][n][r] + b4[r];
                if (RELU) t = fmaxf(t, 0.f);
                v[r] = t * c4[r] * pm;
            }
            if (OUT_F32) {
#pragma unroll
                for (int r = 0; r < 4; ++r)
                    out_f32[((size_t)b * Cout + o0 + ob + r) * HWn + p] = v[r];
            } else {
                ushort4 H, L;
                H.x = bf_hi(v[0]); L.x = bf_hi(v[0] - bf_f(H.x));
                H.y = bf_hi(v[1]); L.y = bf_hi(v[1] - bf_f(H.y));
                H.z = bf_hi(v[2]); L.z = bf_hi(v[2] - bf_f(H.z));
                H.w = bf_hi(v[3]); L.w = bf_hi(v[3] - bf_f(H.w));
                size_t base = ((size_t)b * HWn + p) * 128 + o0 + ob;
                *(ushort4*)&out_hi[base] = H;
                *(ushort4*)&out_lo[base] = L;
            }
        }
    }
}

// ---------------- coord-att: row/col means of h3 (NCHW f32) ----------------
__global__ __launch_bounds__(128) void rowcol_mean_kernel(const float* __restrict__ h3,
        float* __restrict__ xh, float* __restrict__ xw)
{
    __shared__ float t[HWn];
    int bc = blockIdx.x;
    const float* p = h3 + (size_t)bc * HWn;
    for (int i = threadIdx.x; i < HWn; i += 128) t[i] = p[i];
    __syncthreads();
    int tid = threadIdx.x;
    if (tid < 56) {
        float s = 0.f;
#pragma unroll
        for (int i = 0; i < 56; ++i) s += t[tid * 56 + i];
        xh[(size_t)bc * 56 + tid] = s / 56.f;
    } else if (tid >= 64 && tid < 120) {
        int c = tid - 64;
        float s = 0.f;
#pragma unroll
        for (int i = 0; i < 56; ++i) s += t[i * 56 + c];
        xw[(size_t)bc * 56 + c] = s / 56.f;
    }
}

__global__ __launch_bounds__(256) void ca_y_kernel(const float* __restrict__ xh,
        const float* __restrict__ xw, const float* __restrict__ w1c,
        const float* __restrict__ b1c, float* __restrict__ y)
{
    int b = blockIdx.x;
    int t = blockIdx.y;
    __shared__ float src[512];
    __shared__ float part[16][17];
    for (int c = threadIdx.x; c < 512; c += 256)
        src[c] = (t < 56) ? xh[((size_t)b * 512 + c) * 56 + t]
                          : xw[((size_t)b * 512 + c) * 56 + (t - 56)];
    __syncthreads();
    int m  = threadIdx.x & 15;
    int cp = threadIdx.x >> 4;
    float s = 0.f;
#pragma unroll 8
    for (int i = 0; i < 32; ++i) {
        int c = cp * 32 + i;
        s = fmaf(w1c[(size_t)m * 512 + c], src[c], s);
    }
    part[m][cp] = s;
    __syncthreads();
    if (threadIdx.x < 16) {
        float v = b1c[threadIdx.x];
#pragma unroll
        for (int i = 0; i < 16; ++i) v += part[threadIdx.x][i];
        float r6 = fminf(fmaxf(v + 3.f, 0.f), 6.f);
        y[((size_t)b * 16 + threadIdx.x) * 112 + t] = v * r6 / 6.f;
    }
}

__global__ __launch_bounds__(512) void ca_a_kernel(const float* __restrict__ y,
        const float* __restrict__ wh, const float* __restrict__ bh,
        const float* __restrict__ wwp, const float* __restrict__ bw,
        float* __restrict__ ah, float* __restrict__ aw)
{
    int r = blockIdx.x;
    int side = blockIdx.y;
    int b = blockIdx.z;
    int o = threadIdx.x;
    __shared__ float ys[16];
    if (threadIdx.x < 16)
        ys[threadIdx.x] = y[((size_t)b * 16 + threadIdx.x) * 112 + side * 56 + r];
    __syncthreads();
    const float* wmat = side ? wwp : wh;
    float s = (side ? bw : bh)[o];
#pragma unroll
    for (int m = 0; m < 16; ++m) s = fmaf(wmat[o * 16 + m], ys[m], s);
    float sig = 1.f / (1.f + expf(-s));
    (side ? aw : ah)[((size_t)b * 512 + o) * 56 + r] = sig;
}

__global__ __launch_bounds__(256) void finalize_kernel(const float* __restrict__ x,
        const float* __restrict__ ah, const float* __restrict__ aw, float* __restrict__ out)
{
    int e = blockIdx.x * 256 + threadIdx.x;
    int pq = e % 784;
    int bc = e / 784;
    int p = pq * 4;
    int py = p / 56, px = p % 56;
    float4 h = *((const float4*)out + e);
    float4 xv = *((const float4*)x + e);
    float a_h = ah[(size_t)bc * 56 + py];
    float4 a_w = *(const float4*)&aw[(size_t)bc * 56 + px];
    float4 v;
    v.x = fmaxf(h.x * a_h * a_w.x + xv.x, 0.f);
    v.y = fmaxf(h.y * a_h * a_w.y + xv.y, 0.f);
    v.z = fmaxf(h.z * a_h * a_w.z + xv.z, 0.f);
    v.w = fmaxf(h.w * a_h * a_w.w + xv.w, 0.f);
    *((float4*)out + e) = v;
}

extern "C" void kernel_launch(void* const* d_in, const int* in_sizes, int n_in,
                              void* d_out, int out_size, void* d_ws, size_t ws_size,
                              hipStream_t stream)
{
    (void)in_sizes; (void)n_in; (void)out_size; (void)ws_size;
    const float* x     = (const float*)d_in[0];
    const float* sm_w  = (const float*)d_in[1];
    const float* sm_b  = (const float*)d_in[2];
    const float* cm1_w = (const float*)d_in[3];
    const float* cm1_b = (const float*)d_in[4];
    const float* cm2_w = (const float*)d_in[5];
    const float* cm2_b = (const float*)d_in[6];
    const float* cm3_w = (const float*)d_in[7];
    const float* cm3_b = (const float*)d_in[8];
    const float* w1    = (const float*)d_in[9];
    const float* b1    = (const float*)d_in[10];
    const float* w2    = (const float*)d_in[11];
    const float* b2    = (const float*)d_in[12];
    const float* w3    = (const float*)d_in[13];
    const float* b3    = (const float*)d_in[14];
    const float* ca_w1 = (const float*)d_in[15];
    const float* ca_b1 = (const float*)d_in[16];
    const float* ca_wh = (const float*)d_in[17];
    const float* ca_bh = (const float*)d_in[18];
    const float* ca_ww = (const float*)d_in[19];
    const float* ca_bw = (const float*)d_in[20];
    float* out = (float*)d_out;

    // ---- workspace layout ----
    float* fp = (float*)d_ws;
    float* pooled_x  = fp;              fp += 8192;   // pooled_x + h1 + h2 contiguous for one zero
    float* pooled_h1 = fp;              fp += 2048;
    float* pooled_h2 = fp;              fp += 2048;
    float* cm1m      = fp;              fp += 2048;
    float* cm2m      = fp;              fp += 2048;
    float* cm3m      = fp;              fp += 8192;
    float* smask     = fp;              fp += 50176;
    float* sdil      = fp;              fp += 50176;
    float* slog_part = fp;              fp += 401408;
    ushortT* up = (ushortT*)fp;
    ushortT* w1h = up;                  up += 65536;
    ushortT* w1l = up;                  up += 65536;
    ushortT* w2h = up;                  up += 147456;
    ushortT* w2l = up;                  up += 147456;
    ushortT* w3h = up;                  up += 65536;
    ushortT* w3l = up;                  up += 65536;
    ushortT* h1h = up;                  up += 6422528;
    ushortT* h1l = up;                  up += 6422528;
    ushortT* h2h = up;                  up += 6422528;
    ushortT* h2l = up;                  up += 6422528;
    // coord-att scratch aliases h1 (dead after conv2)
    float* xh  = (float*)h1h;
    float* xwm = xh + 458752;
    float* yb  = xwm + 458752;
    float* ah  = yb + 28672;
    float* aw  = ah + 458752;

    zero_kernel<<<48, 256, 0, stream>>>(pooled_x, 12288);
    mask_pool_kernel<<<dim3(25, 8, Bn), 256, 0, stream>>>(x, sm_w, slog_part, pooled_x);
    thresh_kernel<<<196, 256, 0, stream>>>(slog_part, sm_b, smask);
    dilate_kernel<<<dim3(Bn, 13), 256, 0, stream>>>(smask, sdil);
    chan_mask_kernel<<<Bn, 128, 0, stream>>>(pooled_x, cm1_w, cm1_b, cm1m, 512, 128);
    split_w_kernel<<<256, 256, 0, stream>>>(w1, w1h, w1l, 65536);
    split_w2_kernel<<<576, 256, 0, stream>>>(w2, w2h, w2l);
    split_w_kernel<<<256, 256, 0, stream>>>(w3, w3h, w3l, 65536);

    // conv1: 1x1, K=512 f32 input, relu, masks cm1*sdil -> h1 (transposed split bf16)
    mfma_conv_kernel<512, 1, true, true, false><<<dim3(25, 2, Bn), 128, 0, stream>>>(
        x, nullptr, nullptr, w1h, w1l, b1, cm1m, sdil, nullptr, h1h, h1l, 128);

    pool_meanT_kernel<<<dim3(Bn, 8), 256, 0, stream>>>(h1h, h1l, pooled_h1);
    chan_mask_kernel<<<Bn, 128, 0, stream>>>(pooled_h1, cm2_w, cm2_b, cm2m, 128, 128);

    // conv2: 3x3 as 9 taps, K=128, relu, masks cm2*smask -> h2
    mfma_conv_kernel<128, 9, true, false, false><<<dim3(25, 2, Bn), 128, 0, stream>>>(
        nullptr, h1h, h1l, w2h, w2l, b2, cm2m, smask, nullptr, h2h, h2l, 128);

    pool_meanT_kernel<<<dim3(Bn, 8), 256, 0, stream>>>(h2h, h2l, pooled_h2);
    chan_mask_kernel<<<Bn, 512, 0, stream>>>(pooled_h2, cm3_w, cm3_b, cm3m, 128, 512);

    // conv3: 1x1, K=128, no relu, masks cm3*smask -> out (NCHW f32)
    mfma_conv_kernel<128, 1, false, false, true><<<dim3(25, 8, Bn), 128, 0, stream>>>(
        nullptr, h2h, h2l, w3h, w3l, b3, cm3m, smask, out, nullptr, nullptr, 512);

    rowcol_mean_kernel<<<Bn * 512, 128, 0, stream>>>(out, xh, xwm);
    ca_y_kernel<<<dim3(Bn, 112), 256, 0, stream>>>(xh, xwm, ca_w1, ca_b1, yb);
    ca_a_kernel<<<dim3(W56, 2, Bn), 512, 0, stream>>>(yb, ca_wh, ca_bh, ca_ww, ca_bw, ah, aw);
    finalize_kernel<<<25088, 256, 0, stream>>>(x, ah, aw, out);
}